// Round 14
// baseline (779.390 us; speedup 1.0000x reference)
//
#include <hip/hip_runtime.h>
#include <cstddef>

#define B_ 256
#define T_ 128
#define F_ 256
#define H_ 512
#define C_ 10

#define TEAMS 32     // teams; team owns BS batch rows
#define TB    8      // blocks per team (8 x 512-thread blocks, 1/CU)
#define BS    8      // batch rows per team
#define NS    64     // n columns per member block

typedef short bf16x8 __attribute__((ext_vector_type(8)));
typedef float f32x4  __attribute__((ext_vector_type(4)));

// round-to-nearest-even fp32 -> bf16
__device__ __forceinline__ unsigned short f2bf_rn(float f) {
    unsigned u = __builtin_bit_cast(unsigned, f);
    u += 0x7fffu + ((u >> 16) & 1u);
    return (unsigned short)(u >> 16);
}
__device__ __forceinline__ float bf2f(unsigned short s) {
    unsigned u = (unsigned)s << 16;
    return __builtin_bit_cast(float, u);
}
// pack h as split-bf16: low16 = hi, high16 = lo(residual). Same 4 B as f32,
// same numerics as the consumer-side split it replaces.
__device__ __forceinline__ unsigned packh(float h) {
    unsigned short hi = f2bf_rn(h);
    unsigned short lo = f2bf_rn(h - bf2f(hi));
    return (unsigned)hi | ((unsigned)lo << 16);
}

// ---------------------------------------------------------------------------
// GEMM: proj0 = x @ W_ih0^T + b1 + b2 via split-bf16 MFMA (r17 proven).
// BM=BN=128, BK=32, 4 waves x 64x64 quadrant, 3-term split-bf16.
// ---------------------------------------------------------------------------
__global__ __launch_bounds__(256, 2) void gemm_mfma_kernel(
    const float* __restrict__ A, const float* __restrict__ W,
    const float* __restrict__ b1, const float* __restrict__ b2,
    float* __restrict__ Cout)
{
    __shared__ alignas(16) unsigned short Ahi[128 * 32];   // 8 KB
    __shared__ alignas(16) unsigned short Alo[128 * 32];   // 8 KB
    __shared__ alignas(16) unsigned short Bhi[128 * 32];   // 8 KB
    __shared__ alignas(16) unsigned short Blo[128 * 32];   // 8 KB

    const int tid  = threadIdx.x;
    const int m0   = blockIdx.x * 128;
    const int n0   = blockIdx.y * 128;
    const int lane = tid & 63;
    const int wv   = tid >> 6;          // 4 waves
    const int wr   = (wv >> 1) << 6;    // quadrant row: 0 or 64
    const int wc   = (wv & 1) << 6;     // quadrant col: 0 or 64

    f32x4 acc[4][4];
#pragma unroll
    for (int i = 0; i < 4; i++)
#pragma unroll
        for (int j = 0; j < 4; j++) acc[i][j] = f32x4{0.f, 0.f, 0.f, 0.f};

    float bias[4];
#pragma unroll
    for (int ct = 0; ct < 4; ct++) {
        const int n = n0 + wc + ct * 16 + (lane & 15);
        bias[ct] = b1[n] + b2[n];
    }

    const int kcol  = tid & 15;              // k-pair slot (2 floats)
    const int rbase = tid >> 4;              // staging row base
    const int koct2 = (lane >> 4) << 4;      // k-octet byte offset (0..48)

    for (int k0 = 0; k0 < F_; k0 += 32) {
        // ---- stage A and W 128x32 tiles as split-bf16 (8 rows/thread) ----
#pragma unroll
        for (int i = 0; i < 8; i++) {
            const int row = rbase + 16 * i;
            float2 av = *(const float2*)(A + (size_t)(m0 + row) * F_ + k0 + kcol * 2);
            float2 wv2 = *(const float2*)(W + (size_t)(n0 + row) * F_ + k0 + kcol * 2);
            const int addr = ((row << 6) | (kcol << 2)) ^ ((row & 7) << 4);
            unsigned short h0, h1;
            h0 = f2bf_rn(av.x); h1 = f2bf_rn(av.y);
            *(unsigned*)((char*)Ahi + addr) =
                (unsigned)h0 | ((unsigned)h1 << 16);
            *(unsigned*)((char*)Alo + addr) =
                (unsigned)f2bf_rn(av.x - bf2f(h0)) |
                ((unsigned)f2bf_rn(av.y - bf2f(h1)) << 16);
            h0 = f2bf_rn(wv2.x); h1 = f2bf_rn(wv2.y);
            *(unsigned*)((char*)Bhi + addr) =
                (unsigned)h0 | ((unsigned)h1 << 16);
            *(unsigned*)((char*)Blo + addr) =
                (unsigned)f2bf_rn(wv2.x - bf2f(h0)) |
                ((unsigned)f2bf_rn(wv2.y - bf2f(h1)) << 16);
        }
        __syncthreads();

        // ---- fragments + 48 MFMA ----
        bf16x8 fah[4], fal[4], fbh[4], fbl[4];
#pragma unroll
        for (int rt = 0; rt < 4; rt++) {
            const int r = wr + rt * 16 + (lane & 15);
            const int addr = ((r << 6) | koct2) ^ ((r & 7) << 4);
            fah[rt] = *(const bf16x8*)((const char*)Ahi + addr);
            fal[rt] = *(const bf16x8*)((const char*)Alo + addr);
        }
#pragma unroll
        for (int ct = 0; ct < 4; ct++) {
            const int c = wc + ct * 16 + (lane & 15);
            const int addr = ((c << 6) | koct2) ^ ((c & 7) << 4);
            fbh[ct] = *(const bf16x8*)((const char*)Bhi + addr);
            fbl[ct] = *(const bf16x8*)((const char*)Blo + addr);
        }
#pragma unroll
        for (int rt = 0; rt < 4; rt++)
#pragma unroll
            for (int ct = 0; ct < 4; ct++) {
                acc[rt][ct] = __builtin_amdgcn_mfma_f32_16x16x32_bf16(
                    fah[rt], fbh[ct], acc[rt][ct], 0, 0, 0);
                acc[rt][ct] = __builtin_amdgcn_mfma_f32_16x16x32_bf16(
                    fah[rt], fbl[ct], acc[rt][ct], 0, 0, 0);
                acc[rt][ct] = __builtin_amdgcn_mfma_f32_16x16x32_bf16(
                    fal[rt], fbh[ct], acc[rt][ct], 0, 0, 0);
            }
        __syncthreads();
    }

    // ---- epilogue: C/D col=lane&15, row=(lane>>4)*4+q ----
#pragma unroll
    for (int rt = 0; rt < 4; rt++) {
        const int m = m0 + wr + rt * 16 + ((lane >> 4) << 2);
#pragma unroll
        for (int ct = 0; ct < 4; ct++) {
            const int n = n0 + wc + ct * 16 + (lane & 15);
#pragma unroll
            for (int q = 0; q < 4; q++)
                Cout[(size_t)(m + q) * H_ + n] = acc[rt][ct][q] + bias[ct];
        }
    }
}

// ---------------------------------------------------------------------------
// W fragment loader: B-operand [k][n] = W[n][k], split-bf16 hi/lo, 8 ks.
// B-frag layout (16x16x32): col = lane&15, k = khalf + ks*32 + (lane>>4)*8+j.
// Atomic-pinned 8B loads (r7-proven pattern), one-time setup cost.
// ---------------------------------------------------------------------------
__device__ __forceinline__ void load_wfrag(
    const float* __restrict__ W, int wrow, int khalf, int koct,
    bf16x8* bhi, bf16x8* blo)
{
#pragma unroll
    for (int ks = 0; ks < 8; ks++) {
        const float* wp = W + (size_t)wrow * H_ + khalf + ks * 32 + koct;
        const unsigned long long* q = (const unsigned long long*)wp;
        float f[8];
#pragma unroll
        for (int j = 0; j < 4; j++) {
            union { unsigned long long q; float f[2]; } u;
            u.q = __hip_atomic_load(q + j, __ATOMIC_RELAXED,
                                    __HIP_MEMORY_SCOPE_AGENT);
            f[2 * j] = u.f[0]; f[2 * j + 1] = u.f[1];
        }
#pragma unroll
        for (int j = 0; j < 8; j++) {
            unsigned short hi = f2bf_rn(f[j]);
            unsigned short lo = f2bf_rn(f[j] - bf2f(hi));
            bhi[ks][j] = (short)hi;
            blo[ks][j] = (short)lo;
        }
    }
}

// ---------------------------------------------------------------------------
// FUSED dual-layer scan — r22 structure (slot barrier + packed transport);
// round-23 change: ALL-THREAD SLOT POLLING. The release __syncthreads and
// the tid0->block detection broadcast are removed from the serial chain:
// after the drain-sync + tid0 signal, EVERY thread polls the 8 slots and
// proceeds directly into its stage loads once it observes min >= r+1.
// Safety unchanged: per-thread observation of slots >= r+1 implies the
// covered h-data is visible (same monotonic agent-scope protocol); every
// member's tid0 signals unconditionally after the drain-sync (no circular
// wait); hs* write-after-read is fenced by the post-stage and post-MFMA
// __syncthreads between any read and the next round's write.
//   h0(r)   = relu(proj0(r) + Whh0 @ h0(r-1))                    [r < T_]
//   h1(r-1) = relu(Wih1 @ h0(r-1) + b1i+b1h + Whh1 @ h1(r-2))    [r >= 1]
// ---------------------------------------------------------------------------
__global__ __launch_bounds__(512, 2) void fused_scan_kernel(
    float* __restrict__ ws0, unsigned* __restrict__ ws1p,
    const float* __restrict__ Whh0, const float* __restrict__ Wih1,
    const float* __restrict__ Whh1,
    const float* __restrict__ bih1, const float* __restrict__ bhh1,
    unsigned int* __restrict__ bar)
{
    __shared__ alignas(16) unsigned short hs0_hi[BS * H_];  // 8 KB
    __shared__ alignas(16) unsigned short hs0_lo[BS * H_];  // 8 KB
    __shared__ alignas(16) unsigned short hs1_hi[BS * H_];  // 8 KB
    __shared__ alignas(16) unsigned short hs1_lo[BS * H_];  // 8 KB
    __shared__ alignas(16) float red0[8][8][17];            // 4.25 KB
    __shared__ alignas(16) float red1[8][8][17];            // 4.25 KB

    const int tid   = threadIdx.x;          // 0..511
    const int team  = blockIdx.x & 31;      // members stride 32 -> same XCD
    const int mem   = blockIdx.x >> 5;      // 0..7
    const int b0    = team * BS;
    const int n0    = mem * NS;
    const int lane  = tid & 63;
    const int wv    = tid >> 6;             // wave 0..7
    const int ct    = wv >> 1;              // col-tile 0..3 (16 cols each)
    const int khalf = (wv & 1) << 8;        // k in [khalf, khalf+256)

    unsigned int* slots = bar + team * 16;  // 64 B line: 8 member slots

    // ---- register-stationary weight fragments: 3 matrices, k-half each ----
    const int wrow = n0 + (ct << 4) + (lane & 15);
    const int koct = (lane >> 4) << 3;
    bf16x8 w0hi[8], w0lo[8], wihi[8], wilo[8], w1hi[8], w1lo[8];
    load_wfrag(Whh0, wrow, khalf, koct, w0hi, w0lo);
    load_wfrag(Wih1, wrow, khalf, koct, wihi, wilo);
    load_wfrag(Whh1, wrow, khalf, koct, w1hi, w1lo);

    // ---- per-thread output slot: row = tid>>6 (0..7), col = tid&63 ----
    const int bb = tid >> 6;
    const int cc = tid & 63;
    float*    p0 = ws0  + ((size_t)(b0 + bb) * T_) * H_ + n0 + cc;
    unsigned* p1 = ws1p + ((size_t)(b0 + bb) * T_) * H_ + n0 + cc;
    float projv = *p0;                                    // proj0(0) prefetch
    const float bias1v = bih1[n0 + cc] + bhh1[n0 + cc];

    // staging split: qword (u32-pair) within row + row-half
    const int qw    = tid & 255;            // 0..255 (256 pairs = 512 elems)
    const int rhalf = (tid >> 8) * 4;       // rows 0-3 or 4-7

    // A-frag read address pieces (row = lane&7; bit3 rows are duplicates)
    const int arow  = lane & 7;
    const int rbase = arow << 10;           // row * 1024 bytes
    const int kxor  = arow << 4;            // swizzle XOR (bits 4-6)
    const int klane = (lane >> 4) << 4;     // k-octet byte offset

    for (int r = 0; r <= T_; r++) {
        // ---- stage h0(r-1), h1(r-2) (PACKED) into swizzled LDS ----
        if (r == 0) {
            ((float4*)hs0_hi)[tid] = float4{0.f, 0.f, 0.f, 0.f};
            ((float4*)hs0_lo)[tid] = float4{0.f, 0.f, 0.f, 0.f};
        } else {
            const unsigned* sp =
                (const unsigned*)ws0 + ((size_t)b0 * T_ + (r - 1)) * H_;
#pragma unroll
            for (int i = 0; i < 4; i++) {
                const int b = rhalf + i;
                unsigned long long v = __hip_atomic_load(
                    (const unsigned long long*)(sp + (size_t)b * T_ * H_) + qw,
                    __ATOMIC_RELAXED, __HIP_MEMORY_SCOPE_AGENT);
                const unsigned u0 = (unsigned)v, u1 = (unsigned)(v >> 32);
                const int addr = ((b << 10) | (qw << 2)) ^ (b << 4);
                *(unsigned*)((char*)hs0_hi + addr) =
                    (u0 & 0xFFFFu) | (u1 << 16);
                *(unsigned*)((char*)hs0_lo + addr) =
                    (u0 >> 16) | (u1 & 0xFFFF0000u);
            }
        }
        if (r <= 1) {
            ((float4*)hs1_hi)[tid] = float4{0.f, 0.f, 0.f, 0.f};
            ((float4*)hs1_lo)[tid] = float4{0.f, 0.f, 0.f, 0.f};
        } else {
            const unsigned* sp =
                ws1p + ((size_t)b0 * T_ + (r - 2)) * H_;
#pragma unroll
            for (int i = 0; i < 4; i++) {
                const int b = rhalf + i;
                unsigned long long v = __hip_atomic_load(
                    (const unsigned long long*)(sp + (size_t)b * T_ * H_) + qw,
                    __ATOMIC_RELAXED, __HIP_MEMORY_SCOPE_AGENT);
                const unsigned u0 = (unsigned)v, u1 = (unsigned)(v >> 32);
                const int addr = ((b << 10) | (qw << 2)) ^ (b << 4);
                *(unsigned*)((char*)hs1_hi + addr) =
                    (u0 & 0xFFFFu) | (u1 << 16);
                *(unsigned*)((char*)hs1_lo + addr) =
                    (u0 >> 16) | (u1 & 0xFFFF0000u);
            }
        }
        __syncthreads();

        // ---- 3 matmuls over this wave's (col-tile, k-half) slot ----
        f32x4 a0x = {0.f,0.f,0.f,0.f}, a0y = {0.f,0.f,0.f,0.f};
        f32x4 a1x = {0.f,0.f,0.f,0.f}, a1y = {0.f,0.f,0.f,0.f};
#pragma unroll
        for (int ks = 0; ks < 8; ks++) {
            const int kbyte = (khalf << 1) + ks * 64 + klane;
            const int addr  = rbase | (kbyte ^ kxor);
            bf16x8 h0hi = *(const bf16x8*)((const char*)hs0_hi + addr);
            bf16x8 h0lo = *(const bf16x8*)((const char*)hs0_lo + addr);
            bf16x8 h1hi = *(const bf16x8*)((const char*)hs1_hi + addr);
            bf16x8 h1lo = *(const bf16x8*)((const char*)hs1_lo + addr);
            if ((ks & 1) == 0) {
                a0x = __builtin_amdgcn_mfma_f32_16x16x32_bf16(h0hi, w0hi[ks], a0x, 0, 0, 0);
                a0x = __builtin_amdgcn_mfma_f32_16x16x32_bf16(h0hi, w0lo[ks], a0x, 0, 0, 0);
                a0x = __builtin_amdgcn_mfma_f32_16x16x32_bf16(h0lo, w0hi[ks], a0x, 0, 0, 0);
                a1x = __builtin_amdgcn_mfma_f32_16x16x32_bf16(h0hi, wihi[ks], a1x, 0, 0, 0);
                a1x = __builtin_amdgcn_mfma_f32_16x16x32_bf16(h0hi, wilo[ks], a1x, 0, 0, 0);
                a1x = __builtin_amdgcn_mfma_f32_16x16x32_bf16(h0lo, wihi[ks], a1x, 0, 0, 0);
                a1x = __builtin_amdgcn_mfma_f32_16x16x32_bf16(h1hi, w1hi[ks], a1x, 0, 0, 0);
                a1x = __builtin_amdgcn_mfma_f32_16x16x32_bf16(h1hi, w1lo[ks], a1x, 0, 0, 0);
                a1x = __builtin_amdgcn_mfma_f32_16x16x32_bf16(h1lo, w1hi[ks], a1x, 0, 0, 0);
            } else {
                a0y = __builtin_amdgcn_mfma_f32_16x16x32_bf16(h0hi, w0hi[ks], a0y, 0, 0, 0);
                a0y = __builtin_amdgcn_mfma_f32_16x16x32_bf16(h0hi, w0lo[ks], a0y, 0, 0, 0);
                a0y = __builtin_amdgcn_mfma_f32_16x16x32_bf16(h0lo, w0hi[ks], a0y, 0, 0, 0);
                a1y = __builtin_amdgcn_mfma_f32_16x16x32_bf16(h0hi, wihi[ks], a1y, 0, 0, 0);
                a1y = __builtin_amdgcn_mfma_f32_16x16x32_bf16(h0hi, wilo[ks], a1y, 0, 0, 0);
                a1y = __builtin_amdgcn_mfma_f32_16x16x32_bf16(h0lo, wihi[ks], a1y, 0, 0, 0);
                a1y = __builtin_amdgcn_mfma_f32_16x16x32_bf16(h1hi, w1hi[ks], a1y, 0, 0, 0);
                a1y = __builtin_amdgcn_mfma_f32_16x16x32_bf16(h1hi, w1lo[ks], a1y, 0, 0, 0);
                a1y = __builtin_amdgcn_mfma_f32_16x16x32_bf16(h1lo, w1hi[ks], a1y, 0, 0, 0);
            }
        }

        // ---- per-wave k-half partials -> LDS. C/D: col=lane&15,
        // row=(lane>>4)*4+reg; rows 0-7 live in lanes 0-31.
        if (lane < 32) {
            const int rrow = (lane >> 4) << 2;
            const int col  = lane & 15;
#pragma unroll
            for (int q = 0; q < 4; q++) {
                red0[wv][rrow + q][col] = a0x[q] + a0y[q];
                red1[wv][rrow + q][col] = a1x[q] + a1y[q];
            }
        }
        __syncthreads();

        // ---- epilogue: 1 slot/thread/layer; pack + publish ----
        {
            const int wv0 = (cc >> 4) << 1;   // waves ct*2, ct*2+1
            const int ci  = cc & 15;
            if (r < T_) {
                float s0 = red0[wv0][bb][ci] + red0[wv0 + 1][bb][ci];
                float h  = fmaxf(s0 + projv, 0.f);
                __hip_atomic_store((unsigned*)(p0 + (size_t)r * H_), packh(h),
                                   __ATOMIC_RELAXED, __HIP_MEMORY_SCOPE_AGENT);
            }
            if (r >= 1) {
                float s1 = red1[wv0][bb][ci] + red1[wv0 + 1][bb][ci];
                float h  = fmaxf(s1 + bias1v, 0.f);
                __hip_atomic_store(p1 + (size_t)(r - 1) * H_, packh(h),
                                   __ATOMIC_RELAXED, __HIP_MEMORY_SCOPE_AGENT);
            }
        }

        // ---- team barrier: drain-sync + signal + ALL-THREAD poll ----
        if (r < T_) {
            __syncthreads();   // drains vmcnt(0): h-stores visible pre-signal
            if (tid == 0)
                __hip_atomic_store(slots + mem, (unsigned)(r + 1),
                                   __ATOMIC_RELAXED, __HIP_MEMORY_SCOPE_AGENT);
            float nextproj = 0.f;
            if (r + 1 < T_)
                nextproj = p0[(size_t)(r + 1) * H_];   // fp32 proj, read
                                                       // before overwrite
            {
                const unsigned target = (unsigned)(r + 1);
                const unsigned long long* s64 =
                    (const unsigned long long*)slots;
                for (;;) {
                    unsigned long long v0 = __hip_atomic_load(
                        s64 + 0, __ATOMIC_RELAXED, __HIP_MEMORY_SCOPE_AGENT);
                    unsigned long long v1 = __hip_atomic_load(
                        s64 + 1, __ATOMIC_RELAXED, __HIP_MEMORY_SCOPE_AGENT);
                    unsigned long long v2 = __hip_atomic_load(
                        s64 + 2, __ATOMIC_RELAXED, __HIP_MEMORY_SCOPE_AGENT);
                    unsigned long long v3 = __hip_atomic_load(
                        s64 + 3, __ATOMIC_RELAXED, __HIP_MEMORY_SCOPE_AGENT);
                    unsigned a = (unsigned)v0, b2 = (unsigned)(v0 >> 32);
                    unsigned c = (unsigned)v1, d = (unsigned)(v1 >> 32);
                    unsigned e = (unsigned)v2, f = (unsigned)(v2 >> 32);
                    unsigned g = (unsigned)v3, h = (unsigned)(v3 >> 32);
                    unsigned m0v = a < b2 ? a : b2;
                    unsigned m1v = c < d ? c : d;
                    unsigned m2v = e < f ? e : f;
                    unsigned m3v = g < h ? g : h;
                    unsigned mv  = m0v < m1v ? m0v : m1v;
                    unsigned mw  = m2v < m3v ? m2v : m3v;
                    if ((mv < mw ? mv : mw) >= target) break;
                    __builtin_amdgcn_s_sleep(1);
                }
            }
            projv = nextproj;
            // no release sync: each thread proceeds straight to its stage
            // loads; hs* WAR is fenced by the post-stage __syncthreads.
        }
    }
}

// ---------------------------------------------------------------------------
// FC head: out[b][c] = sum_i h1[b][i] * Wfc[c][i] + bfc[c]
// h1 arrives PACKED (hi|lo<<16); reconstruct h = hi + lo exactly
// (r15-verified). 1024 threads/block (16 waves/CU, r20 proven).
// ---------------------------------------------------------------------------
__global__ __launch_bounds__(1024) void fc_kernel(
    const unsigned* __restrict__ Hl, const float* __restrict__ Wfc,
    const float* __restrict__ bfc, float* __restrict__ out)
{
    const int b = blockIdx.x;
    const int tid = threadIdx.x;
    const unsigned* hb = Hl + (size_t)b * (T_ * H_);

    float acc[C_];
#pragma unroll
    for (int c = 0; c < C_; c++) acc[c] = 0.f;

    for (int i = tid * 4; i < T_ * H_; i += 1024 * 4) {
        uint4 hv = *(const uint4*)(hb + i);
        float h0 = bf2f((unsigned short)(hv.x & 0xFFFFu)) +
                   bf2f((unsigned short)(hv.x >> 16));
        float h1 = bf2f((unsigned short)(hv.y & 0xFFFFu)) +
                   bf2f((unsigned short)(hv.y >> 16));
        float h2 = bf2f((unsigned short)(hv.z & 0xFFFFu)) +
                   bf2f((unsigned short)(hv.z >> 16));
        float h3 = bf2f((unsigned short)(hv.w & 0xFFFFu)) +
                   bf2f((unsigned short)(hv.w >> 16));
#pragma unroll
        for (int c = 0; c < C_; c++) {
            float4 wv = *(const float4*)(Wfc + (size_t)c * (T_ * H_) + i);
            acc[c] = fmaf(h0, wv.x, fmaf(h1, wv.y,
                     fmaf(h2, wv.z, fmaf(h3, wv.w, acc[c]))));
        }
    }

    __shared__ float red[16][C_];
#pragma unroll
    for (int c = 0; c < C_; c++) {
        float v = acc[c];
#pragma unroll
        for (int off = 32; off >= 1; off >>= 1) v += __shfl_xor(v, off, 64);
        if ((tid & 63) == 0) red[tid >> 6][c] = v;
    }
    __syncthreads();
    if (tid < C_) {
        float v = bfc[tid];
#pragma unroll
        for (int w = 0; w < 16; w++) v += red[w][tid];
        out[(size_t)b * C_ + tid] = v;
    }
}

// ---------------------------------------------------------------------------
// Pipeline (round-23): MFMA proj0 GEMM -> FUSED scan (all-thread-poll slot
// barrier, packed transport) -> FC (packed read, 1024-thr). Barrier slots:
// 32 teams x 16 dwords in the first 2 KB of d_out (zeroed by hipMemsetAsync
// — graph-safe; fc_kernel fully overwrites d_out at the end).
// ---------------------------------------------------------------------------
extern "C" void kernel_launch(void* const* d_in, const int* in_sizes, int n_in,
                              void* d_out, int out_size, void* d_ws, size_t ws_size,
                              hipStream_t stream)
{
    (void)in_sizes; (void)n_in; (void)out_size; (void)ws_size;

    const float* x    = (const float*)d_in[0];
    const float* Wih0 = (const float*)d_in[1];
    const float* Whh0 = (const float*)d_in[2];
    const float* bih0 = (const float*)d_in[3];
    const float* bhh0 = (const float*)d_in[4];
    const float* Wih1 = (const float*)d_in[5];
    const float* Whh1 = (const float*)d_in[6];
    const float* bih1 = (const float*)d_in[7];
    const float* bhh1 = (const float*)d_in[8];
    const float* Wfc  = (const float*)d_in[9];
    const float* bfc  = (const float*)d_in[10];
    float* out = (float*)d_out;

    float*    ws0  = (float*)d_ws;                    // [B][T][H] proj0/h0
    unsigned* ws1p = (unsigned*)(ws0 + (size_t)B_ * T_ * H_); // packed h1
    unsigned int* bar = (unsigned int*)d_out;         // TEAMS x 16 dwords

    hipMemsetAsync(bar, 0, TEAMS * 16 * sizeof(unsigned int), stream);

    dim3 gproj(B_ * T_ / 128, H_ / 128);   // (256, 4)

    gemm_mfma_kernel<<<gproj, 256, 0, stream>>>(x, Wih0, bih0, bhh0, ws0);
    fused_scan_kernel<<<TEAMS * TB, 512, 0, stream>>>(
        ws0, ws1p, Whh0, Wih1, Whh1, bih1, bhh1, bar);
    fc_kernel<<<B_, 1024, 0, stream>>>(ws1p, Wfc, bfc, out);
}

// Round 15
// 756.442 us; speedup vs baseline: 1.0303x; 1.0303x over previous
//
#include <hip/hip_runtime.h>
#include <cstddef>

#define B_ 256
#define T_ 128
#define F_ 256
#define H_ 512
#define C_ 10

#define TEAMS 32     // teams; team owns BS batch rows
#define TB    8      // blocks per team (8 x 512-thread blocks, 1/CU)
#define BS    8      // batch rows per team
#define NS    64     // n columns per member block

typedef short bf16x8 __attribute__((ext_vector_type(8)));
typedef float f32x4  __attribute__((ext_vector_type(4)));

// round-to-nearest-even fp32 -> bf16
__device__ __forceinline__ unsigned short f2bf_rn(float f) {
    unsigned u = __builtin_bit_cast(unsigned, f);
    u += 0x7fffu + ((u >> 16) & 1u);
    return (unsigned short)(u >> 16);
}
__device__ __forceinline__ float bf2f(unsigned short s) {
    unsigned u = (unsigned)s << 16;
    return __builtin_bit_cast(float, u);
}
// pack h as split-bf16: low16 = hi, high16 = lo(residual). Same 4 B as f32,
// same numerics as the consumer-side split it replaces.
__device__ __forceinline__ unsigned packh(float h) {
    unsigned short hi = f2bf_rn(h);
    unsigned short lo = f2bf_rn(h - bf2f(hi));
    return (unsigned)hi | ((unsigned)lo << 16);
}

// ---------------------------------------------------------------------------
// GEMM: proj0 = x @ W_ih0^T + b1 + b2 via split-bf16 MFMA (r17 proven).
// BM=BN=128, BK=32, 4 waves x 64x64 quadrant, 3-term split-bf16.
// ---------------------------------------------------------------------------
__global__ __launch_bounds__(256, 2) void gemm_mfma_kernel(
    const float* __restrict__ A, const float* __restrict__ W,
    const float* __restrict__ b1, const float* __restrict__ b2,
    float* __restrict__ Cout)
{
    __shared__ alignas(16) unsigned short Ahi[128 * 32];   // 8 KB
    __shared__ alignas(16) unsigned short Alo[128 * 32];   // 8 KB
    __shared__ alignas(16) unsigned short Bhi[128 * 32];   // 8 KB
    __shared__ alignas(16) unsigned short Blo[128 * 32];   // 8 KB

    const int tid  = threadIdx.x;
    const int m0   = blockIdx.x * 128;
    const int n0   = blockIdx.y * 128;
    const int lane = tid & 63;
    const int wv   = tid >> 6;          // 4 waves
    const int wr   = (wv >> 1) << 6;    // quadrant row: 0 or 64
    const int wc   = (wv & 1) << 6;     // quadrant col: 0 or 64

    f32x4 acc[4][4];
#pragma unroll
    for (int i = 0; i < 4; i++)
#pragma unroll
        for (int j = 0; j < 4; j++) acc[i][j] = f32x4{0.f, 0.f, 0.f, 0.f};

    float bias[4];
#pragma unroll
    for (int ct = 0; ct < 4; ct++) {
        const int n = n0 + wc + ct * 16 + (lane & 15);
        bias[ct] = b1[n] + b2[n];
    }

    const int kcol  = tid & 15;              // k-pair slot (2 floats)
    const int rbase = tid >> 4;              // staging row base
    const int koct2 = (lane >> 4) << 4;      // k-octet byte offset (0..48)

    for (int k0 = 0; k0 < F_; k0 += 32) {
        // ---- stage A and W 128x32 tiles as split-bf16 (8 rows/thread) ----
#pragma unroll
        for (int i = 0; i < 8; i++) {
            const int row = rbase + 16 * i;
            float2 av = *(const float2*)(A + (size_t)(m0 + row) * F_ + k0 + kcol * 2);
            float2 wv2 = *(const float2*)(W + (size_t)(n0 + row) * F_ + k0 + kcol * 2);
            const int addr = ((row << 6) | (kcol << 2)) ^ ((row & 7) << 4);
            unsigned short h0, h1;
            h0 = f2bf_rn(av.x); h1 = f2bf_rn(av.y);
            *(unsigned*)((char*)Ahi + addr) =
                (unsigned)h0 | ((unsigned)h1 << 16);
            *(unsigned*)((char*)Alo + addr) =
                (unsigned)f2bf_rn(av.x - bf2f(h0)) |
                ((unsigned)f2bf_rn(av.y - bf2f(h1)) << 16);
            h0 = f2bf_rn(wv2.x); h1 = f2bf_rn(wv2.y);
            *(unsigned*)((char*)Bhi + addr) =
                (unsigned)h0 | ((unsigned)h1 << 16);
            *(unsigned*)((char*)Blo + addr) =
                (unsigned)f2bf_rn(wv2.x - bf2f(h0)) |
                ((unsigned)f2bf_rn(wv2.y - bf2f(h1)) << 16);
        }
        __syncthreads();

        // ---- fragments + 48 MFMA ----
        bf16x8 fah[4], fal[4], fbh[4], fbl[4];
#pragma unroll
        for (int rt = 0; rt < 4; rt++) {
            const int r = wr + rt * 16 + (lane & 15);
            const int addr = ((r << 6) | koct2) ^ ((r & 7) << 4);
            fah[rt] = *(const bf16x8*)((const char*)Ahi + addr);
            fal[rt] = *(const bf16x8*)((const char*)Alo + addr);
        }
#pragma unroll
        for (int ct = 0; ct < 4; ct++) {
            const int c = wc + ct * 16 + (lane & 15);
            const int addr = ((c << 6) | koct2) ^ ((c & 7) << 4);
            fbh[ct] = *(const bf16x8*)((const char*)Bhi + addr);
            fbl[ct] = *(const bf16x8*)((const char*)Blo + addr);
        }
#pragma unroll
        for (int rt = 0; rt < 4; rt++)
#pragma unroll
            for (int ct = 0; ct < 4; ct++) {
                acc[rt][ct] = __builtin_amdgcn_mfma_f32_16x16x32_bf16(
                    fah[rt], fbh[ct], acc[rt][ct], 0, 0, 0);
                acc[rt][ct] = __builtin_amdgcn_mfma_f32_16x16x32_bf16(
                    fah[rt], fbl[ct], acc[rt][ct], 0, 0, 0);
                acc[rt][ct] = __builtin_amdgcn_mfma_f32_16x16x32_bf16(
                    fal[rt], fbh[ct], acc[rt][ct], 0, 0, 0);
            }
        __syncthreads();
    }

    // ---- epilogue: C/D col=lane&15, row=(lane>>4)*4+q ----
#pragma unroll
    for (int rt = 0; rt < 4; rt++) {
        const int m = m0 + wr + rt * 16 + ((lane >> 4) << 2);
#pragma unroll
        for (int ct = 0; ct < 4; ct++) {
            const int n = n0 + wc + ct * 16 + (lane & 15);
#pragma unroll
            for (int q = 0; q < 4; q++)
                Cout[(size_t)(m + q) * H_ + n] = acc[rt][ct][q] + bias[ct];
        }
    }
}

// ---------------------------------------------------------------------------
// W fragment loader: B-operand [k][n] = W[n][k], split-bf16 hi/lo, 8 ks.
// B-frag layout (16x16x32): col = lane&15, k = khalf + ks*32 + (lane>>4)*8+j.
// Atomic-pinned 8B loads (r7-proven pattern), one-time setup cost.
// ---------------------------------------------------------------------------
__device__ __forceinline__ void load_wfrag(
    const float* __restrict__ W, int wrow, int khalf, int koct,
    bf16x8* bhi, bf16x8* blo)
{
#pragma unroll
    for (int ks = 0; ks < 8; ks++) {
        const float* wp = W + (size_t)wrow * H_ + khalf + ks * 32 + koct;
        const unsigned long long* q = (const unsigned long long*)wp;
        float f[8];
#pragma unroll
        for (int j = 0; j < 4; j++) {
            union { unsigned long long q; float f[2]; } u;
            u.q = __hip_atomic_load(q + j, __ATOMIC_RELAXED,
                                    __HIP_MEMORY_SCOPE_AGENT);
            f[2 * j] = u.f[0]; f[2 * j + 1] = u.f[1];
        }
#pragma unroll
        for (int j = 0; j < 8; j++) {
            unsigned short hi = f2bf_rn(f[j]);
            unsigned short lo = f2bf_rn(f[j] - bf2f(hi));
            bhi[ks][j] = (short)hi;
            blo[ks][j] = (short)lo;
        }
    }
}

// ---------------------------------------------------------------------------
// FUSED dual-layer scan — FINAL (r22, 765.4 us proven): slot barrier with
// single-poller (r23's all-thread poll REGRESSED: 512x poll streams per team
// line serialize in the IF$ — detection choreography was cheaper than poll
// contention) + producer-side packed h transport.
// Transport/barrier primitives: relaxed agent-scope atomics, __syncthreads()
// drains vmcnt(0) before the signal, monotonic per-member slot stores + u64
// poll (no RMW), proj prefetch rides the spin. Banned (hang/regress ledger):
// flag+ballot (r6/r8), plain-store/sc0 (r16), all-thread poll (r23).
//   h0(r)   = relu(proj0(r) + Whh0 @ h0(r-1))                    [r < T_]
//   h1(r-1) = relu(Wih1 @ h0(r-1) + b1i+b1h + Whh1 @ h1(r-2))    [r >= 1]
// Scan is LATENCY-bound (MfmaUtil 20%, HBM 5%, VALUBusy 12%): the floor is
// the T=128-deep serial chain of IF$-scope store->signal->detect->reload.
// ---------------------------------------------------------------------------
__global__ __launch_bounds__(512, 2) void fused_scan_kernel(
    float* __restrict__ ws0, unsigned* __restrict__ ws1p,
    const float* __restrict__ Whh0, const float* __restrict__ Wih1,
    const float* __restrict__ Whh1,
    const float* __restrict__ bih1, const float* __restrict__ bhh1,
    unsigned int* __restrict__ bar)
{
    __shared__ alignas(16) unsigned short hs0_hi[BS * H_];  // 8 KB
    __shared__ alignas(16) unsigned short hs0_lo[BS * H_];  // 8 KB
    __shared__ alignas(16) unsigned short hs1_hi[BS * H_];  // 8 KB
    __shared__ alignas(16) unsigned short hs1_lo[BS * H_];  // 8 KB
    __shared__ alignas(16) float red0[8][8][17];            // 4.25 KB
    __shared__ alignas(16) float red1[8][8][17];            // 4.25 KB

    const int tid   = threadIdx.x;          // 0..511
    const int team  = blockIdx.x & 31;      // members stride 32 -> same XCD
    const int mem   = blockIdx.x >> 5;      // 0..7
    const int b0    = team * BS;
    const int n0    = mem * NS;
    const int lane  = tid & 63;
    const int wv    = tid >> 6;             // wave 0..7
    const int ct    = wv >> 1;              // col-tile 0..3 (16 cols each)
    const int khalf = (wv & 1) << 8;        // k in [khalf, khalf+256)

    unsigned int* slots = bar + team * 16;  // 64 B line: 8 member slots

    // ---- register-stationary weight fragments: 3 matrices, k-half each ----
    const int wrow = n0 + (ct << 4) + (lane & 15);
    const int koct = (lane >> 4) << 3;
    bf16x8 w0hi[8], w0lo[8], wihi[8], wilo[8], w1hi[8], w1lo[8];
    load_wfrag(Whh0, wrow, khalf, koct, w0hi, w0lo);
    load_wfrag(Wih1, wrow, khalf, koct, wihi, wilo);
    load_wfrag(Whh1, wrow, khalf, koct, w1hi, w1lo);

    // ---- per-thread output slot: row = tid>>6 (0..7), col = tid&63 ----
    const int bb = tid >> 6;
    const int cc = tid & 63;
    float*    p0 = ws0  + ((size_t)(b0 + bb) * T_) * H_ + n0 + cc;
    unsigned* p1 = ws1p + ((size_t)(b0 + bb) * T_) * H_ + n0 + cc;
    float projv = *p0;                                    // proj0(0) prefetch
    const float bias1v = bih1[n0 + cc] + bhh1[n0 + cc];

    // staging split: qword (u32-pair) within row + row-half
    const int qw    = tid & 255;            // 0..255 (256 pairs = 512 elems)
    const int rhalf = (tid >> 8) * 4;       // rows 0-3 or 4-7

    // A-frag read address pieces (row = lane&7; bit3 rows are duplicates)
    const int arow  = lane & 7;
    const int rbase = arow << 10;           // row * 1024 bytes
    const int kxor  = arow << 4;            // swizzle XOR (bits 4-6)
    const int klane = (lane >> 4) << 4;     // k-octet byte offset

    for (int r = 0; r <= T_; r++) {
        // ---- stage h0(r-1), h1(r-2) (PACKED) into swizzled LDS ----
        if (r == 0) {
            ((float4*)hs0_hi)[tid] = float4{0.f, 0.f, 0.f, 0.f};
            ((float4*)hs0_lo)[tid] = float4{0.f, 0.f, 0.f, 0.f};
        } else {
            const unsigned* sp =
                (const unsigned*)ws0 + ((size_t)b0 * T_ + (r - 1)) * H_;
#pragma unroll
            for (int i = 0; i < 4; i++) {
                const int b = rhalf + i;
                unsigned long long v = __hip_atomic_load(
                    (const unsigned long long*)(sp + (size_t)b * T_ * H_) + qw,
                    __ATOMIC_RELAXED, __HIP_MEMORY_SCOPE_AGENT);
                const unsigned u0 = (unsigned)v, u1 = (unsigned)(v >> 32);
                const int addr = ((b << 10) | (qw << 2)) ^ (b << 4);
                *(unsigned*)((char*)hs0_hi + addr) =
                    (u0 & 0xFFFFu) | (u1 << 16);
                *(unsigned*)((char*)hs0_lo + addr) =
                    (u0 >> 16) | (u1 & 0xFFFF0000u);
            }
        }
        if (r <= 1) {
            ((float4*)hs1_hi)[tid] = float4{0.f, 0.f, 0.f, 0.f};
            ((float4*)hs1_lo)[tid] = float4{0.f, 0.f, 0.f, 0.f};
        } else {
            const unsigned* sp =
                ws1p + ((size_t)b0 * T_ + (r - 2)) * H_;
#pragma unroll
            for (int i = 0; i < 4; i++) {
                const int b = rhalf + i;
                unsigned long long v = __hip_atomic_load(
                    (const unsigned long long*)(sp + (size_t)b * T_ * H_) + qw,
                    __ATOMIC_RELAXED, __HIP_MEMORY_SCOPE_AGENT);
                const unsigned u0 = (unsigned)v, u1 = (unsigned)(v >> 32);
                const int addr = ((b << 10) | (qw << 2)) ^ (b << 4);
                *(unsigned*)((char*)hs1_hi + addr) =
                    (u0 & 0xFFFFu) | (u1 << 16);
                *(unsigned*)((char*)hs1_lo + addr) =
                    (u0 >> 16) | (u1 & 0xFFFF0000u);
            }
        }
        __syncthreads();

        // ---- 3 matmuls over this wave's (col-tile, k-half) slot ----
        f32x4 a0x = {0.f,0.f,0.f,0.f}, a0y = {0.f,0.f,0.f,0.f};
        f32x4 a1x = {0.f,0.f,0.f,0.f}, a1y = {0.f,0.f,0.f,0.f};
#pragma unroll
        for (int ks = 0; ks < 8; ks++) {
            const int kbyte = (khalf << 1) + ks * 64 + klane;
            const int addr  = rbase | (kbyte ^ kxor);
            bf16x8 h0hi = *(const bf16x8*)((const char*)hs0_hi + addr);
            bf16x8 h0lo = *(const bf16x8*)((const char*)hs0_lo + addr);
            bf16x8 h1hi = *(const bf16x8*)((const char*)hs1_hi + addr);
            bf16x8 h1lo = *(const bf16x8*)((const char*)hs1_lo + addr);
            if ((ks & 1) == 0) {
                a0x = __builtin_amdgcn_mfma_f32_16x16x32_bf16(h0hi, w0hi[ks], a0x, 0, 0, 0);
                a0x = __builtin_amdgcn_mfma_f32_16x16x32_bf16(h0hi, w0lo[ks], a0x, 0, 0, 0);
                a0x = __builtin_amdgcn_mfma_f32_16x16x32_bf16(h0lo, w0hi[ks], a0x, 0, 0, 0);
                a1x = __builtin_amdgcn_mfma_f32_16x16x32_bf16(h0hi, wihi[ks], a1x, 0, 0, 0);
                a1x = __builtin_amdgcn_mfma_f32_16x16x32_bf16(h0hi, wilo[ks], a1x, 0, 0, 0);
                a1x = __builtin_amdgcn_mfma_f32_16x16x32_bf16(h0lo, wihi[ks], a1x, 0, 0, 0);
                a1x = __builtin_amdgcn_mfma_f32_16x16x32_bf16(h1hi, w1hi[ks], a1x, 0, 0, 0);
                a1x = __builtin_amdgcn_mfma_f32_16x16x32_bf16(h1hi, w1lo[ks], a1x, 0, 0, 0);
                a1x = __builtin_amdgcn_mfma_f32_16x16x32_bf16(h1lo, w1hi[ks], a1x, 0, 0, 0);
            } else {
                a0y = __builtin_amdgcn_mfma_f32_16x16x32_bf16(h0hi, w0hi[ks], a0y, 0, 0, 0);
                a0y = __builtin_amdgcn_mfma_f32_16x16x32_bf16(h0hi, w0lo[ks], a0y, 0, 0, 0);
                a0y = __builtin_amdgcn_mfma_f32_16x16x32_bf16(h0lo, w0hi[ks], a0y, 0, 0, 0);
                a1y = __builtin_amdgcn_mfma_f32_16x16x32_bf16(h0hi, wihi[ks], a1y, 0, 0, 0);
                a1y = __builtin_amdgcn_mfma_f32_16x16x32_bf16(h0hi, wilo[ks], a1y, 0, 0, 0);
                a1y = __builtin_amdgcn_mfma_f32_16x16x32_bf16(h0lo, wihi[ks], a1y, 0, 0, 0);
                a1y = __builtin_amdgcn_mfma_f32_16x16x32_bf16(h1hi, w1hi[ks], a1y, 0, 0, 0);
                a1y = __builtin_amdgcn_mfma_f32_16x16x32_bf16(h1hi, w1lo[ks], a1y, 0, 0, 0);
                a1y = __builtin_amdgcn_mfma_f32_16x16x32_bf16(h1lo, w1hi[ks], a1y, 0, 0, 0);
            }
        }

        // ---- per-wave k-half partials -> LDS. C/D: col=lane&15,
        // row=(lane>>4)*4+reg; rows 0-7 live in lanes 0-31.
        if (lane < 32) {
            const int rrow = (lane >> 4) << 2;
            const int col  = lane & 15;
#pragma unroll
            for (int q = 0; q < 4; q++) {
                red0[wv][rrow + q][col] = a0x[q] + a0y[q];
                red1[wv][rrow + q][col] = a1x[q] + a1y[q];
            }
        }
        __syncthreads();

        // ---- epilogue: 1 slot/thread/layer; pack + publish ----
        {
            const int wv0 = (cc >> 4) << 1;   // waves ct*2, ct*2+1
            const int ci  = cc & 15;
            if (r < T_) {
                float s0 = red0[wv0][bb][ci] + red0[wv0 + 1][bb][ci];
                float h  = fmaxf(s0 + projv, 0.f);
                __hip_atomic_store((unsigned*)(p0 + (size_t)r * H_), packh(h),
                                   __ATOMIC_RELAXED, __HIP_MEMORY_SCOPE_AGENT);
            }
            if (r >= 1) {
                float s1 = red1[wv0][bb][ci] + red1[wv0 + 1][bb][ci];
                float h  = fmaxf(s1 + bias1v, 0.f);
                __hip_atomic_store(p1 + (size_t)(r - 1) * H_, packh(h),
                                   __ATOMIC_RELAXED, __HIP_MEMORY_SCOPE_AGENT);
            }
        }

        // ---- team barrier (slot signal, no RMW); proj prefetch rides it ----
        if (r < T_) {
            __syncthreads();   // drains vmcnt(0): h-stores visible pre-signal
            if (tid == 0)
                __hip_atomic_store(slots + mem, (unsigned)(r + 1),
                                   __ATOMIC_RELAXED, __HIP_MEMORY_SCOPE_AGENT);
            float nextproj = 0.f;
            if (r + 1 < T_)
                nextproj = p0[(size_t)(r + 1) * H_];   // fp32 proj, read
            if (tid == 0) {                            // before overwrite
                const unsigned target = (unsigned)(r + 1);
                const unsigned long long* s64 =
                    (const unsigned long long*)slots;
                for (;;) {
                    unsigned long long v0 = __hip_atomic_load(
                        s64 + 0, __ATOMIC_RELAXED, __HIP_MEMORY_SCOPE_AGENT);
                    unsigned long long v1 = __hip_atomic_load(
                        s64 + 1, __ATOMIC_RELAXED, __HIP_MEMORY_SCOPE_AGENT);
                    unsigned long long v2 = __hip_atomic_load(
                        s64 + 2, __ATOMIC_RELAXED, __HIP_MEMORY_SCOPE_AGENT);
                    unsigned long long v3 = __hip_atomic_load(
                        s64 + 3, __ATOMIC_RELAXED, __HIP_MEMORY_SCOPE_AGENT);
                    unsigned a = (unsigned)v0, b2 = (unsigned)(v0 >> 32);
                    unsigned c = (unsigned)v1, d = (unsigned)(v1 >> 32);
                    unsigned e = (unsigned)v2, f = (unsigned)(v2 >> 32);
                    unsigned g = (unsigned)v3, h = (unsigned)(v3 >> 32);
                    unsigned m0v = a < b2 ? a : b2;
                    unsigned m1v = c < d ? c : d;
                    unsigned m2v = e < f ? e : f;
                    unsigned m3v = g < h ? g : h;
                    unsigned mv  = m0v < m1v ? m0v : m1v;
                    unsigned mw  = m2v < m3v ? m2v : m3v;
                    if ((mv < mw ? mv : mw) >= target) break;
                    __builtin_amdgcn_s_sleep(1);
                }
            }
            __syncthreads();   // release block; prefetch drains here too
            projv = nextproj;
        }
    }
}

// ---------------------------------------------------------------------------
// FC head: out[b][c] = sum_i h1[b][i] * Wfc[c][i] + bfc[c]
// h1 arrives PACKED (hi|lo<<16); reconstruct h = hi + lo exactly
// (r15-verified). 1024 threads/block (16 waves/CU, r20 proven).
// ---------------------------------------------------------------------------
__global__ __launch_bounds__(1024) void fc_kernel(
    const unsigned* __restrict__ Hl, const float* __restrict__ Wfc,
    const float* __restrict__ bfc, float* __restrict__ out)
{
    const int b = blockIdx.x;
    const int tid = threadIdx.x;
    const unsigned* hb = Hl + (size_t)b * (T_ * H_);

    float acc[C_];
#pragma unroll
    for (int c = 0; c < C_; c++) acc[c] = 0.f;

    for (int i = tid * 4; i < T_ * H_; i += 1024 * 4) {
        uint4 hv = *(const uint4*)(hb + i);
        float h0 = bf2f((unsigned short)(hv.x & 0xFFFFu)) +
                   bf2f((unsigned short)(hv.x >> 16));
        float h1 = bf2f((unsigned short)(hv.y & 0xFFFFu)) +
                   bf2f((unsigned short)(hv.y >> 16));
        float h2 = bf2f((unsigned short)(hv.z & 0xFFFFu)) +
                   bf2f((unsigned short)(hv.z >> 16));
        float h3 = bf2f((unsigned short)(hv.w & 0xFFFFu)) +
                   bf2f((unsigned short)(hv.w >> 16));
#pragma unroll
        for (int c = 0; c < C_; c++) {
            float4 wv = *(const float4*)(Wfc + (size_t)c * (T_ * H_) + i);
            acc[c] = fmaf(h0, wv.x, fmaf(h1, wv.y,
                     fmaf(h2, wv.z, fmaf(h3, wv.w, acc[c]))));
        }
    }

    __shared__ float red[16][C_];
#pragma unroll
    for (int c = 0; c < C_; c++) {
        float v = acc[c];
#pragma unroll
        for (int off = 32; off >= 1; off >>= 1) v += __shfl_xor(v, off, 64);
        if ((tid & 63) == 0) red[tid >> 6][c] = v;
    }
    __syncthreads();
    if (tid < C_) {
        float v = bfc[tid];
#pragma unroll
        for (int w = 0; w < 16; w++) v += red[w][tid];
        out[(size_t)b * C_ + tid] = v;
    }
}

// ---------------------------------------------------------------------------
// Pipeline (FINAL = r22): MFMA proj0 GEMM -> FUSED scan (slot barrier,
// packed transport) -> FC (packed read, 1024-thr). Barrier slots: 32 teams
// x 16 dwords in the first 2 KB of d_out (zeroed by hipMemsetAsync —
// graph-safe; fc_kernel fully overwrites d_out at the end).
// ---------------------------------------------------------------------------
extern "C" void kernel_launch(void* const* d_in, const int* in_sizes, int n_in,
                              void* d_out, int out_size, void* d_ws, size_t ws_size,
                              hipStream_t stream)
{
    (void)in_sizes; (void)n_in; (void)out_size; (void)ws_size;

    const float* x    = (const float*)d_in[0];
    const float* Wih0 = (const float*)d_in[1];
    const float* Whh0 = (const float*)d_in[2];
    const float* bih0 = (const float*)d_in[3];
    const float* bhh0 = (const float*)d_in[4];
    const float* Wih1 = (const float*)d_in[5];
    const float* Whh1 = (const float*)d_in[6];
    const float* bih1 = (const float*)d_in[7];
    const float* bhh1 = (const float*)d_in[8];
    const float* Wfc  = (const float*)d_in[9];
    const float* bfc  = (const float*)d_in[10];
    float* out = (float*)d_out;

    float*    ws0  = (float*)d_ws;                    // [B][T][H] proj0/h0
    unsigned* ws1p = (unsigned*)(ws0 + (size_t)B_ * T_ * H_); // packed h1
    unsigned int* bar = (unsigned int*)d_out;         // TEAMS x 16 dwords

    hipMemsetAsync(bar, 0, TEAMS * 16 * sizeof(unsigned int), stream);

    dim3 gproj(B_ * T_ / 128, H_ / 128);   // (256, 4)

    gemm_mfma_kernel<<<gproj, 256, 0, stream>>>(x, Wih0, bih0, bhh0, ws0);
    fused_scan_kernel<<<TEAMS * TB, 512, 0, stream>>>(
        ws0, ws1p, Whh0, Wih1, Whh1, bih1, bhh1, bar);
    fc_kernel<<<B_, 1024, 0, stream>>>(ws1p, Wfc, bfc, out);
}